// Round 3
// baseline (117.819 us; speedup 1.0000x reference)
//
#include <hip/hip_runtime.h>
#include <math.h>

#define NT 5
#define NB 8
#define NC 32
#define NH 256
#define NW 256
#define NHW (NH * NW)        // 65536
#define NBC (NB * NC)        // 256
#define NTBC (NT * NBC)      // 1280
#define KS 7
#define PAD 3
#define VIS_TH 0.1f

#define QRT 4                     // quarters per row
#define NUNITS (NTBC * QRT)       // 5120 work units
#define EPQ (NHW / QRT)           // elements per quarter = 16384
#define V4PQ (EPQ / 4)            // float4 per quarter = 4096
#define ITER (V4PQ / 256)         // 16 iters per thread per unit
#define GRID 1024                 // resident grid: 4 blocks/CU * 256 CU
#define UPB (NUNITS / GRID)       // 5 units per block

typedef float vf4 __attribute__((ext_vector_type(4)));

// ---------- helpers ----------

__device__ __forceinline__ void make_k1(float k[KS]) {
    float s = 0.f;
#pragma unroll
    for (int i = 0; i < KS; ++i) {
        float xx = (float)i - 3.0f;
        float t = xx / 1.5f;
        k[i] = expf(-0.5f * t * t);
        s += k[i];
    }
    float inv = 1.0f / s;
#pragma unroll
    for (int i = 0; i < KS; ++i) k[i] *= inv;
}

__device__ __forceinline__ int refl(int z) {
    z = (z < 0) ? -z : z;
    z = (z >= NH) ? (2 * NH - 2 - z) : z;
    return z;
}

__device__ __forceinline__ float rweight(int y, int r, const float k1[KS]) {
    float s = 0.f;
#pragma unroll
    for (int d = 0; d < KS; ++d) {
        int z = y + d - PAD;
        if (refl(z) == r) s += k1[d];
    }
    return s;
}

__device__ __forceinline__ float rwmax(int r, const float k1[KS]) {
    float m = 0.f;
#pragma unroll
    for (int y = 0; y < KS; ++y) m = fmaxf(m, rweight(y, r, k1));
    int lo = max(0, r - PAD), hi = min(NH - 1, r + PAD);
    for (int y = lo; y <= hi; ++y) m = fmaxf(m, rweight(y, r, k1));
#pragma unroll
    for (int y = NH - KS; y < NH; ++y) m = fmaxf(m, rweight(y, r, k1));
    return m;
}

// ---------- kernel 1: persistent grid-stride partial argmax ----------
// 1024 blocks (exactly resident at 4 blocks/CU); each handles 5 units of
// 16K elements. No residency tail, single smooth DRAM stream.

__global__ __launch_bounds__(256, 4) void k_argmax(
        const float* __restrict__ x, const float* __restrict__ urnd,
        float* __restrict__ pmx, int* __restrict__ parg) {
    const int tid = threadIdx.x;
    __shared__ float sv[4];
    __shared__ int si[4];

    for (int k = 0; k < UPB; ++k) {
        const int u = blockIdx.x + GRID * k;   // unit id
        const int row = u >> 2;                // t*NBC + bc
        const int q = u & (QRT - 1);
        const int bc = row & (NBC - 1);

        const vf4* u4 = (const vf4*)urnd + (size_t)row * (NHW / 4) + q * V4PQ;
        const vf4* x4 = (const vf4*)x + (size_t)bc * (NHW / 4) + q * V4PQ;

        float b0 = -1.f, b1 = -1.f, b2 = -1.f, b3 = -1.f;
        int i0 = 0, i1 = 0, i2 = 0, i3 = 0;

#pragma unroll 8
        for (int j = 0; j < ITER; ++j) {
            int v = j * 256 + tid;
            vf4 uu = __builtin_nontemporal_load(u4 + v);
            vf4 xx = x4[v];
            float s0 = 1.f / (1.f + expf(-xx[0]));
            float s1 = 1.f / (1.f + expf(-xx[1]));
            float s2 = 1.f / (1.f + expf(-xx[2]));
            float s3 = 1.f / (1.f + expf(-xx[3]));
            float p0 = s0 * uu[0], p1 = s1 * uu[1];
            float p2 = s2 * uu[2], p3 = s3 * uu[3];
            int base = v * 4;
            if (p0 > b0) { b0 = p0; i0 = base; }
            if (p1 > b1) { b1 = p1; i1 = base + 1; }
            if (p2 > b2) { b2 = p2; i2 = base + 2; }
            if (p3 > b3) { b3 = p3; i3 = base + 3; }
        }

        float best = b0; int bidx = i0;
        if (b1 > best || (b1 == best && i1 < bidx)) { best = b1; bidx = i1; }
        if (b2 > best || (b2 == best && i2 < bidx)) { best = b2; bidx = i2; }
        if (b3 > best || (b3 == best && i3 < bidx)) { best = b3; bidx = i3; }

#pragma unroll
        for (int m = 32; m; m >>= 1) {
            float ov = __shfl_xor(best, m, 64);
            int oi = __shfl_xor(bidx, m, 64);
            if (ov > best || (ov == best && oi < bidx)) { best = ov; bidx = oi; }
        }

        int wid = tid >> 6;
        if ((tid & 63) == 0) { sv[wid] = best; si[wid] = bidx; }
        __syncthreads();
        if (tid == 0) {
#pragma unroll
            for (int w = 1; w < 4; ++w) {
                if (sv[w] > best || (sv[w] == best && si[w] < bidx)) {
                    best = sv[w]; bidx = si[w];
                }
            }
            pmx[u] = best;
            parg[u] = q * EPQ + bidx;    // index within the full row
        }
        __syncthreads();   // protect sv/si reuse in next unit
    }
}

// ---------- kernel 2: fused stats + att write ----------

__global__ __launch_bounds__(256) void k_statt(
        const float* __restrict__ pmx, const int* __restrict__ parg,
        float* __restrict__ out_m, float* __restrict__ out_v,
        float* __restrict__ out_vis, float* __restrict__ att) {
    const int tid = threadIdx.x;     // doubles as "bc" for the stats phase
    const int myc = blockIdx.x;      // the bc this block writes

    float k1[KS];
    make_k1(k1);

    // ---- stats for bc = tid ----
    float ji[NT], jj[NT];
    int visn = 0;
#pragma unroll
    for (int t = 0; t < NT; ++t) {
        int u0 = (t * NBC + tid) * QRT;
        float m = pmx[u0]; int a = parg[u0];
#pragma unroll
        for (int q = 1; q < QRT; ++q) {           // ascending q: ties -> earliest
            float mq = pmx[u0 + q];
            if (mq > m) { m = mq; a = parg[u0 + q]; }
        }
        bool vt = (m >= VIS_TH);
        float ii = (float)(a >> 8) * (1.0f / (float)NH);
        float jv = (float)(a & (NW - 1)) * (1.0f / (float)NW);
        ji[t] = vt ? ii : 0.f;
        jj[t] = vt ? jv : 0.f;
        visn += vt ? 1 : 0;
    }
    float mi = (ji[0] + ji[1] + ji[2] + ji[3] + ji[4]) / 5.0f;
    float mj = (jj[0] + jj[1] + jj[2] + jj[3] + jj[4]) / 5.0f;
    float vi = 0.f, vj = 0.f;
#pragma unroll
    for (int t = 0; t < NT; ++t) {
        float di = ji[t] - mi, dj = jj[t] - mj;
        vi += di * di;
        vj += dj * dj;
    }
    vi /= (float)(NT - 1);
    vj /= (float)(NT - 1);

    bool vis = (visn >= 3);

    if (blockIdx.x == 0) {
        out_m[tid * 2 + 0] = vis ? mi : 0.f;
        out_m[tid * 2 + 1] = vis ? mj : 0.f;
        out_v[tid * 2 + 0] = vis ? vi : 0.f;
        out_v[tid * 2 + 1] = vis ? vj : 0.f;
        out_vis[tid] = vis ? 1.f : 0.f;
    }

    int r = min(max((int)roundf((vis ? mi : 0.f) * (float)NH), 0), NH - 1);
    int c = min(max((int)roundf((vis ? mj : 0.f) * (float)NW), 0), NW - 1);
    float cmax = vis ? (rwmax(r, k1) * rwmax(c, k1)) : 0.f;

    __shared__ int sR[NBC], sC[NBC], sVis[NBC];
    __shared__ float sG[NBC];
    sR[tid] = r; sC[tid] = c; sVis[tid] = vis ? 1 : 0; sG[tid] = cmax;
    __syncthreads();
#pragma unroll
    for (int off = 128; off; off >>= 1) {
        if (tid < off) sG[tid] = fmaxf(sG[tid], sG[tid + off]);
        __syncthreads();
    }
    const float gmax = sG[0];
    const int r_ = sR[myc], c_ = sC[myc], vis_ = sVis[myc];

    vf4* out4 = (vf4*)(att + (size_t)myc * NHW);

    if (!vis_) {
        vf4 z = {0.f, 0.f, 0.f, 0.f};
#pragma unroll 4
        for (int j = 0; j < 64; ++j)
            __builtin_nontemporal_store(z, out4 + j * 256 + tid);
        return;
    }

    __shared__ float sRW[NH];
    sRW[tid] = rweight(tid, r_, k1);
    const int xq = tid & 63;
    const float cw0 = rweight(4 * xq + 0, c_, k1);
    const float cw1 = rweight(4 * xq + 1, c_, k1);
    const float cw2 = rweight(4 * xq + 2, c_, k1);
    const float cw3 = rweight(4 * xq + 3, c_, k1);
    __syncthreads();

    const int w = tid >> 6;
    for (int j = 0; j < 64; ++j) {
        int y = j * 4 + w;
        float rw = sRW[y];
        vf4 o;
        if (rw == 0.f) {
            o = (vf4){0.f, 0.f, 0.f, 0.f};
        } else {
            float r0 = rw * cw0, r1 = rw * cw1, r2 = rw * cw2, r3 = rw * cw3;
            o[0] = (r0 == 0.f) ? 0.f : (r0 / gmax);
            o[1] = (r1 == 0.f) ? 0.f : (r1 / gmax);
            o[2] = (r2 == 0.f) ? 0.f : (r2 / gmax);
            o[3] = (r3 == 0.f) ? 0.f : (r3 / gmax);
        }
        __builtin_nontemporal_store(o, out4 + j * 256 + tid);
    }
}

// ---------- launcher ----------

extern "C" void kernel_launch(void* const* d_in, const int* in_sizes, int n_in,
                              void* d_out, int out_size, void* d_ws, size_t ws_size,
                              hipStream_t stream) {
    const float* x = (const float*)d_in[0];
    const float* urnd = (const float*)d_in[1];

    float* out = (float*)d_out;
    float* out_att = out;                        // [8,32,256,256]
    float* out_m = out + (size_t)NBC * NHW;      // [8,32,2]
    float* out_v = out_m + NBC * 2;              // [8,32,2]
    float* out_vis = out_v + NBC * 2;            // [8,32]

    char* ws = (char*)d_ws;
    float* pmx = (float*)ws;                ws += NUNITS * sizeof(float);
    int* parg = (int*)ws;

    k_argmax<<<GRID, 256, 0, stream>>>(x, urnd, pmx, parg);
    k_statt<<<NBC, 256, 0, stream>>>(pmx, parg, out_m, out_v, out_vis, out_att);
}

// Round 4
// 84.047 us; speedup vs baseline: 1.4018x; 1.4018x over previous
//
#include <hip/hip_runtime.h>
#include <math.h>

#define NT 5
#define NB 8
#define NC 32
#define NH 256
#define NW 256
#define NHW (NH * NW)        // 65536
#define NBC (NB * NC)        // 256
#define NTBC (NT * NBC)      // 1280
#define KS 7
#define PAD 3
#define VIS_TH 0.1f

#define QRT 4                     // quarters per (b,c) plane
#define NUNITS (NTBC * QRT)       // 5120 partial results
#define EPQ (NHW / QRT)           // elements per quarter = 16384
#define V4PQ (EPQ / 4)            // float4 per quarter = 4096
#define ITER (V4PQ / 256)         // 16 iters per thread per unit

typedef float vf4 __attribute__((ext_vector_type(4)));

// ---------- helpers ----------

__device__ __forceinline__ void make_k1(float k[KS]) {
    float s = 0.f;
#pragma unroll
    for (int i = 0; i < KS; ++i) {
        float xx = (float)i - 3.0f;
        float t = xx / 1.5f;
        k[i] = expf(-0.5f * t * t);
        s += k[i];
    }
    float inv = 1.0f / s;
#pragma unroll
    for (int i = 0; i < KS; ++i) k[i] *= inv;
}

__device__ __forceinline__ int refl(int z) {
    z = (z < 0) ? -z : z;
    z = (z >= NH) ? (2 * NH - 2 - z) : z;
    return z;
}

__device__ __forceinline__ float rweight(int y, int r, const float k1[KS]) {
    float s = 0.f;
#pragma unroll
    for (int d = 0; d < KS; ++d) {
        int z = y + d - PAD;
        if (refl(z) == r) s += k1[d];
    }
    return s;
}

__device__ __forceinline__ float rwmax(int r, const float k1[KS]) {
    float m = 0.f;
#pragma unroll
    for (int y = 0; y < KS; ++y) m = fmaxf(m, rweight(y, r, k1));
    int lo = max(0, r - PAD), hi = min(NH - 1, r + PAD);
    for (int y = lo; y <= hi; ++y) m = fmaxf(m, rweight(y, r, k1));
#pragma unroll
    for (int y = NH - KS; y < NH; ++y) m = fmaxf(m, rweight(y, r, k1));
    return m;
}

// ---------- kernel 1: x-read-once argmax ----------
// One block per (bc, quarter): 1024 blocks. Each x element is loaded ONCE,
// sigmoid computed ONCE, then the 5 urnd streams are consumed against it
// (5 independent max-chains). Every input byte read exactly once from HBM.

__global__ __launch_bounds__(256, 4) void k_argmax(
        const float* __restrict__ x, const float* __restrict__ urnd,
        float* __restrict__ pmx, int* __restrict__ parg) {
    const int tid = threadIdx.x;
    const int bc = blockIdx.x >> 2;
    const int q = blockIdx.x & (QRT - 1);

    const vf4* x4 = (const vf4*)x + (size_t)bc * (NHW / 4) + q * V4PQ;
    const vf4* u4 = (const vf4*)urnd + (size_t)bc * (NHW / 4) + q * V4PQ;
    const size_t TS = (size_t)NBC * (NHW / 4);   // t-stride in float4 units

    float bt[NT];
    int it[NT];
#pragma unroll
    for (int t = 0; t < NT; ++t) { bt[t] = -1.f; it[t] = 0; }

#pragma unroll 2
    for (int j = 0; j < ITER; ++j) {
        const int v = j * 256 + tid;
        vf4 xx = __builtin_nontemporal_load(x4 + v);
        const float s0 = 1.f / (1.f + expf(-xx[0]));
        const float s1 = 1.f / (1.f + expf(-xx[1]));
        const float s2 = 1.f / (1.f + expf(-xx[2]));
        const float s3 = 1.f / (1.f + expf(-xx[3]));
        const int base = v * 4;
#pragma unroll
        for (int t = 0; t < NT; ++t) {
            vf4 uu = __builtin_nontemporal_load(u4 + (size_t)t * TS + v);
            float p0 = s0 * uu[0], p1 = s1 * uu[1];
            float p2 = s2 * uu[2], p3 = s3 * uu[3];
            // strict > keeps first occurrence; 5 t-chains give ILP
            if (p0 > bt[t]) { bt[t] = p0; it[t] = base; }
            if (p1 > bt[t]) { bt[t] = p1; it[t] = base + 1; }
            if (p2 > bt[t]) { bt[t] = p2; it[t] = base + 2; }
            if (p3 > bt[t]) { bt[t] = p3; it[t] = base + 3; }
        }
    }

    // wave butterfly reduce per t (tie -> smaller index)
#pragma unroll
    for (int t = 0; t < NT; ++t) {
        float best = bt[t];
        int bidx = it[t];
#pragma unroll
        for (int m = 32; m; m >>= 1) {
            float ov = __shfl_xor(best, m, 64);
            int oi = __shfl_xor(bidx, m, 64);
            if (ov > best || (ov == best && oi < bidx)) { best = ov; bidx = oi; }
        }
        bt[t] = best;
        it[t] = bidx;
    }

    __shared__ float sv[NT][4];
    __shared__ int si[NT][4];
    const int w = tid >> 6;
    if ((tid & 63) == 0) {
#pragma unroll
        for (int t = 0; t < NT; ++t) { sv[t][w] = bt[t]; si[t][w] = it[t]; }
    }
    __syncthreads();
    if (tid < NT) {
        float best = sv[tid][0];
        int bidx = si[tid][0];
#pragma unroll
        for (int ww = 1; ww < 4; ++ww) {
            if (sv[tid][ww] > best || (sv[tid][ww] == best && si[tid][ww] < bidx)) {
                best = sv[tid][ww];
                bidx = si[tid][ww];
            }
        }
        pmx[(tid * NBC + bc) * QRT + q] = best;
        parg[(tid * NBC + bc) * QRT + q] = q * EPQ + bidx;
    }
}

// ---------- kernel 2: fused stats + att write ----------

__global__ __launch_bounds__(256) void k_statt(
        const float* __restrict__ pmx, const int* __restrict__ parg,
        float* __restrict__ out_m, float* __restrict__ out_v,
        float* __restrict__ out_vis, float* __restrict__ att) {
    const int tid = threadIdx.x;     // doubles as "bc" for the stats phase
    const int myc = blockIdx.x;      // the bc this block writes

    float k1[KS];
    make_k1(k1);

    float ji[NT], jj[NT];
    int visn = 0;
#pragma unroll
    for (int t = 0; t < NT; ++t) {
        int u0 = (t * NBC + tid) * QRT;
        float m = pmx[u0]; int a = parg[u0];
#pragma unroll
        for (int q = 1; q < QRT; ++q) {           // ascending q: ties -> earliest
            float mq = pmx[u0 + q];
            if (mq > m) { m = mq; a = parg[u0 + q]; }
        }
        bool vt = (m >= VIS_TH);
        float ii = (float)(a >> 8) * (1.0f / (float)NH);
        float jv = (float)(a & (NW - 1)) * (1.0f / (float)NW);
        ji[t] = vt ? ii : 0.f;
        jj[t] = vt ? jv : 0.f;
        visn += vt ? 1 : 0;
    }
    float mi = (ji[0] + ji[1] + ji[2] + ji[3] + ji[4]) / 5.0f;
    float mj = (jj[0] + jj[1] + jj[2] + jj[3] + jj[4]) / 5.0f;
    float vi = 0.f, vj = 0.f;
#pragma unroll
    for (int t = 0; t < NT; ++t) {
        float di = ji[t] - mi, dj = jj[t] - mj;
        vi += di * di;
        vj += dj * dj;
    }
    vi /= (float)(NT - 1);
    vj /= (float)(NT - 1);

    bool vis = (visn >= 3);

    if (blockIdx.x == 0) {
        out_m[tid * 2 + 0] = vis ? mi : 0.f;
        out_m[tid * 2 + 1] = vis ? mj : 0.f;
        out_v[tid * 2 + 0] = vis ? vi : 0.f;
        out_v[tid * 2 + 1] = vis ? vj : 0.f;
        out_vis[tid] = vis ? 1.f : 0.f;
    }

    int r = min(max((int)roundf((vis ? mi : 0.f) * (float)NH), 0), NH - 1);
    int c = min(max((int)roundf((vis ? mj : 0.f) * (float)NW), 0), NW - 1);
    float cmax = vis ? (rwmax(r, k1) * rwmax(c, k1)) : 0.f;

    __shared__ int sR[NBC], sC[NBC], sVis[NBC];
    __shared__ float sG[NBC];
    sR[tid] = r; sC[tid] = c; sVis[tid] = vis ? 1 : 0; sG[tid] = cmax;
    __syncthreads();
#pragma unroll
    for (int off = 128; off; off >>= 1) {
        if (tid < off) sG[tid] = fmaxf(sG[tid], sG[tid + off]);
        __syncthreads();
    }
    const float gmax = sG[0];
    const int r_ = sR[myc], c_ = sC[myc], vis_ = sVis[myc];

    vf4* out4 = (vf4*)(att + (size_t)myc * NHW);

    if (!vis_) {
        vf4 z = {0.f, 0.f, 0.f, 0.f};
#pragma unroll 4
        for (int j = 0; j < 64; ++j)
            __builtin_nontemporal_store(z, out4 + j * 256 + tid);
        return;
    }

    __shared__ float sRW[NH];
    sRW[tid] = rweight(tid, r_, k1);
    const int xq = tid & 63;
    const float cw0 = rweight(4 * xq + 0, c_, k1);
    const float cw1 = rweight(4 * xq + 1, c_, k1);
    const float cw2 = rweight(4 * xq + 2, c_, k1);
    const float cw3 = rweight(4 * xq + 3, c_, k1);
    __syncthreads();

    const int w = tid >> 6;
    for (int j = 0; j < 64; ++j) {
        int y = j * 4 + w;
        float rw = sRW[y];
        vf4 o;
        if (rw == 0.f) {
            o = (vf4){0.f, 0.f, 0.f, 0.f};
        } else {
            float r0 = rw * cw0, r1 = rw * cw1, r2 = rw * cw2, r3 = rw * cw3;
            o[0] = (r0 == 0.f) ? 0.f : (r0 / gmax);
            o[1] = (r1 == 0.f) ? 0.f : (r1 / gmax);
            o[2] = (r2 == 0.f) ? 0.f : (r2 / gmax);
            o[3] = (r3 == 0.f) ? 0.f : (r3 / gmax);
        }
        __builtin_nontemporal_store(o, out4 + j * 256 + tid);
    }
}

// ---------- launcher ----------

extern "C" void kernel_launch(void* const* d_in, const int* in_sizes, int n_in,
                              void* d_out, int out_size, void* d_ws, size_t ws_size,
                              hipStream_t stream) {
    const float* x = (const float*)d_in[0];
    const float* urnd = (const float*)d_in[1];

    float* out = (float*)d_out;
    float* out_att = out;                        // [8,32,256,256]
    float* out_m = out + (size_t)NBC * NHW;      // [8,32,2]
    float* out_v = out_m + NBC * 2;              // [8,32,2]
    float* out_vis = out_v + NBC * 2;            // [8,32]

    char* ws = (char*)d_ws;
    float* pmx = (float*)ws;                ws += NUNITS * sizeof(float);
    int* parg = (int*)ws;

    k_argmax<<<NBC * QRT, 256, 0, stream>>>(x, urnd, pmx, parg);
    k_statt<<<NBC, 256, 0, stream>>>(pmx, parg, out_m, out_v, out_vis, out_att);
}

// Round 5
// 83.692 us; speedup vs baseline: 1.4078x; 1.0042x over previous
//
#include <hip/hip_runtime.h>
#include <math.h>

#define NT 5
#define NB 8
#define NC 32
#define NH 256
#define NW 256
#define NHW (NH * NW)        // 65536
#define NBC (NB * NC)        // 256
#define NTBC (NT * NBC)      // 1280
#define KS 7
#define PAD 3
#define VIS_TH 0.1f

#define QRT 4                     // quarters per (b,c) plane
#define NUNITS (NTBC * QRT)       // 5120 partial results
#define EPQ (NHW / QRT)           // elements per quarter = 16384
#define V4PQ (EPQ / 4)            // float4 per quarter = 4096
#define ITER (V4PQ / 256)         // 16 iters per thread per unit

typedef float vf4 __attribute__((ext_vector_type(4)));

// ---------- helpers ----------

__device__ __forceinline__ void make_k1(float k[KS]) {
    float s = 0.f;
#pragma unroll
    for (int i = 0; i < KS; ++i) {
        float xx = (float)i - 3.0f;
        float t = xx / 1.5f;
        k[i] = expf(-0.5f * t * t);
        s += k[i];
    }
    float inv = 1.0f / s;
#pragma unroll
    for (int i = 0; i < KS; ++i) k[i] *= inv;
}

__device__ __forceinline__ int refl(int z) {
    z = (z < 0) ? -z : z;
    z = (z >= NH) ? (2 * NH - 2 - z) : z;
    return z;
}

__device__ __forceinline__ float rweight(int y, int r, const float k1[KS]) {
    float s = 0.f;
#pragma unroll
    for (int d = 0; d < KS; ++d) {
        int z = y + d - PAD;
        if (refl(z) == r) s += k1[d];
    }
    return s;
}

__device__ __forceinline__ float rwmax(int r, const float k1[KS]) {
    float m = 0.f;
#pragma unroll
    for (int y = 0; y < KS; ++y) m = fmaxf(m, rweight(y, r, k1));
    int lo = max(0, r - PAD), hi = min(NH - 1, r + PAD);
    for (int y = lo; y <= hi; ++y) m = fmaxf(m, rweight(y, r, k1));
#pragma unroll
    for (int y = NH - KS; y < NH; ++y) m = fmaxf(m, rweight(y, r, k1));
    return m;
}

// ---------- kernel 1: x-read-once argmax (unchanged from round 4) ----------
// One block per (bc, quarter): 1024 blocks. Each x element is loaded ONCE,
// sigmoid computed ONCE, then the 5 urnd streams are consumed against it
// (5 independent max-chains). Every input byte read exactly once from HBM.

__global__ __launch_bounds__(256, 4) void k_argmax(
        const float* __restrict__ x, const float* __restrict__ urnd,
        float* __restrict__ pmx, int* __restrict__ parg) {
    const int tid = threadIdx.x;
    const int bc = blockIdx.x >> 2;
    const int q = blockIdx.x & (QRT - 1);

    const vf4* x4 = (const vf4*)x + (size_t)bc * (NHW / 4) + q * V4PQ;
    const vf4* u4 = (const vf4*)urnd + (size_t)bc * (NHW / 4) + q * V4PQ;
    const size_t TS = (size_t)NBC * (NHW / 4);   // t-stride in float4 units

    float bt[NT];
    int it[NT];
#pragma unroll
    for (int t = 0; t < NT; ++t) { bt[t] = -1.f; it[t] = 0; }

#pragma unroll 2
    for (int j = 0; j < ITER; ++j) {
        const int v = j * 256 + tid;
        vf4 xx = __builtin_nontemporal_load(x4 + v);
        const float s0 = 1.f / (1.f + expf(-xx[0]));
        const float s1 = 1.f / (1.f + expf(-xx[1]));
        const float s2 = 1.f / (1.f + expf(-xx[2]));
        const float s3 = 1.f / (1.f + expf(-xx[3]));
        const int base = v * 4;
#pragma unroll
        for (int t = 0; t < NT; ++t) {
            vf4 uu = __builtin_nontemporal_load(u4 + (size_t)t * TS + v);
            float p0 = s0 * uu[0], p1 = s1 * uu[1];
            float p2 = s2 * uu[2], p3 = s3 * uu[3];
            // strict > keeps first occurrence; 5 t-chains give ILP
            if (p0 > bt[t]) { bt[t] = p0; it[t] = base; }
            if (p1 > bt[t]) { bt[t] = p1; it[t] = base + 1; }
            if (p2 > bt[t]) { bt[t] = p2; it[t] = base + 2; }
            if (p3 > bt[t]) { bt[t] = p3; it[t] = base + 3; }
        }
    }

    // wave butterfly reduce per t (tie -> smaller index)
#pragma unroll
    for (int t = 0; t < NT; ++t) {
        float best = bt[t];
        int bidx = it[t];
#pragma unroll
        for (int m = 32; m; m >>= 1) {
            float ov = __shfl_xor(best, m, 64);
            int oi = __shfl_xor(bidx, m, 64);
            if (ov > best || (ov == best && oi < bidx)) { best = ov; bidx = oi; }
        }
        bt[t] = best;
        it[t] = bidx;
    }

    __shared__ float sv[NT][4];
    __shared__ int si[NT][4];
    const int w = tid >> 6;
    if ((tid & 63) == 0) {
#pragma unroll
        for (int t = 0; t < NT; ++t) { sv[t][w] = bt[t]; si[t][w] = it[t]; }
    }
    __syncthreads();
    if (tid < NT) {
        float best = sv[tid][0];
        int bidx = si[tid][0];
#pragma unroll
        for (int ww = 1; ww < 4; ++ww) {
            if (sv[tid][ww] > best || (sv[tid][ww] == best && si[tid][ww] < bidx)) {
                best = sv[tid][ww];
                bidx = si[tid][ww];
            }
        }
        pmx[(tid * NBC + bc) * QRT + q] = best;
        parg[(tid * NBC + bc) * QRT + q] = q * EPQ + bidx;
    }
}

// ---------- kernel 2: fused stats + att write, 1024 blocks ----------
// Block g handles plane myc = g>>2, row-quarter qy = g&3. Every block
// redundantly computes all-bc stats (40 KB of L2-hit loads) to obtain the
// global max; block 0 also writes the small outputs; each block writes its
// 64-row quarter-plane (16 float4 per thread) for 4x the store parallelism
// of the round-4 version.

__global__ __launch_bounds__(256, 4) void k_statt(
        const float* __restrict__ pmx, const int* __restrict__ parg,
        float* __restrict__ out_m, float* __restrict__ out_v,
        float* __restrict__ out_vis, float* __restrict__ att) {
    const int tid = threadIdx.x;     // doubles as "bc" for the stats phase
    const int myc = blockIdx.x >> 2; // the plane this block writes
    const int qy = blockIdx.x & 3;   // which 64-row band

    float k1[KS];
    make_k1(k1);

    // ---- stats for bc = tid ----
    float ji[NT], jj[NT];
    int visn = 0;
#pragma unroll
    for (int t = 0; t < NT; ++t) {
        int u0 = (t * NBC + tid) * QRT;
        float m = pmx[u0]; int a = parg[u0];
#pragma unroll
        for (int q = 1; q < QRT; ++q) {           // ascending q: ties -> earliest
            float mq = pmx[u0 + q];
            if (mq > m) { m = mq; a = parg[u0 + q]; }
        }
        bool vt = (m >= VIS_TH);
        float ii = (float)(a >> 8) * (1.0f / (float)NH);
        float jv = (float)(a & (NW - 1)) * (1.0f / (float)NW);
        ji[t] = vt ? ii : 0.f;
        jj[t] = vt ? jv : 0.f;
        visn += vt ? 1 : 0;
    }
    float mi = (ji[0] + ji[1] + ji[2] + ji[3] + ji[4]) / 5.0f;
    float mj = (jj[0] + jj[1] + jj[2] + jj[3] + jj[4]) / 5.0f;
    float vi = 0.f, vj = 0.f;
#pragma unroll
    for (int t = 0; t < NT; ++t) {
        float di = ji[t] - mi, dj = jj[t] - mj;
        vi += di * di;
        vj += dj * dj;
    }
    vi /= (float)(NT - 1);
    vj /= (float)(NT - 1);

    bool vis = (visn >= 3);

    if (blockIdx.x == 0) {
        out_m[tid * 2 + 0] = vis ? mi : 0.f;
        out_m[tid * 2 + 1] = vis ? mj : 0.f;
        out_v[tid * 2 + 0] = vis ? vi : 0.f;
        out_v[tid * 2 + 1] = vis ? vj : 0.f;
        out_vis[tid] = vis ? 1.f : 0.f;
    }

    int r = min(max((int)roundf((vis ? mi : 0.f) * (float)NH), 0), NH - 1);
    int c = min(max((int)roundf((vis ? mj : 0.f) * (float)NW), 0), NW - 1);
    float cmax = vis ? (rwmax(r, k1) * rwmax(c, k1)) : 0.f;

    __shared__ int sR[NBC], sC[NBC], sVis[NBC];
    __shared__ float sG[NBC];
    sR[tid] = r; sC[tid] = c; sVis[tid] = vis ? 1 : 0; sG[tid] = cmax;
    __syncthreads();
#pragma unroll
    for (int off = 128; off; off >>= 1) {
        if (tid < off) sG[tid] = fmaxf(sG[tid], sG[tid + off]);
        __syncthreads();
    }
    const float gmax = sG[0];
    const int r_ = sR[myc], c_ = sC[myc], vis_ = sVis[myc];

    // this block's 64-row band: float4 indices qy*4096 + j*256 + tid, j<16
    vf4* out4 = (vf4*)(att + (size_t)myc * NHW) + qy * (NHW / 4 / 4);

    if (!vis_) {
        vf4 z = {0.f, 0.f, 0.f, 0.f};
#pragma unroll
        for (int j = 0; j < 16; ++j)
            __builtin_nontemporal_store(z, out4 + j * 256 + tid);
        return;
    }

    // row of flat index f = qy*4096 + j*256 + tid is y = qy*64 + j*4 + (tid>>6);
    // col quad xq = tid & 63 (j-invariant) -> 4 fixed columns per thread.
    __shared__ float sRW[64];
    if (tid < 64) sRW[tid] = rweight(qy * 64 + tid, r_, k1);
    const int xq = tid & 63;
    const float cw0 = rweight(4 * xq + 0, c_, k1);
    const float cw1 = rweight(4 * xq + 1, c_, k1);
    const float cw2 = rweight(4 * xq + 2, c_, k1);
    const float cw3 = rweight(4 * xq + 3, c_, k1);
    __syncthreads();

    const int w = tid >> 6;
#pragma unroll
    for (int j = 0; j < 16; ++j) {
        float rw = sRW[j * 4 + w];       // wave-uniform broadcast
        vf4 o;
        if (rw == 0.f) {                 // uniform branch: most rows are zero
            o = (vf4){0.f, 0.f, 0.f, 0.f};
        } else {
            float r0 = rw * cw0, r1 = rw * cw1, r2 = rw * cw2, r3 = rw * cw3;
            o[0] = (r0 == 0.f) ? 0.f : (r0 / gmax);
            o[1] = (r1 == 0.f) ? 0.f : (r1 / gmax);
            o[2] = (r2 == 0.f) ? 0.f : (r2 / gmax);
            o[3] = (r3 == 0.f) ? 0.f : (r3 / gmax);
        }
        __builtin_nontemporal_store(o, out4 + j * 256 + tid);
    }
}

// ---------- launcher ----------

extern "C" void kernel_launch(void* const* d_in, const int* in_sizes, int n_in,
                              void* d_out, int out_size, void* d_ws, size_t ws_size,
                              hipStream_t stream) {
    const float* x = (const float*)d_in[0];
    const float* urnd = (const float*)d_in[1];

    float* out = (float*)d_out;
    float* out_att = out;                        // [8,32,256,256]
    float* out_m = out + (size_t)NBC * NHW;      // [8,32,2]
    float* out_v = out_m + NBC * 2;              // [8,32,2]
    float* out_vis = out_v + NBC * 2;            // [8,32]

    char* ws = (char*)d_ws;
    float* pmx = (float*)ws;                ws += NUNITS * sizeof(float);
    int* parg = (int*)ws;

    k_argmax<<<NBC * QRT, 256, 0, stream>>>(x, urnd, pmx, parg);
    k_statt<<<NBC * 4, 256, 0, stream>>>(pmx, parg, out_m, out_v, out_vis, out_att);
}

// Round 7
// 82.713 us; speedup vs baseline: 1.4244x; 1.0118x over previous
//
#include <hip/hip_runtime.h>
#include <math.h>

#define NT 5
#define NB 8
#define NC 32
#define NH 256
#define NW 256
#define NHW (NH * NW)        // 65536
#define NBC (NB * NC)        // 256
#define NTBC (NT * NBC)      // 1280
#define KS 7
#define PAD 3
#define VIS_TH 0.1f

#define QRT 4                     // quarters per (b,c) plane
#define NUNITS (NTBC * QRT)       // 5120 partial results
#define EPQ (NHW / QRT)           // elements per quarter = 16384
#define CHUNK_E 8192              // elements per LDS chunk (32 KB sigmoid)
#define CHUNK_V4 (CHUNK_E / 4)    // 2048 float4
#define JITER (CHUNK_V4 / 256)    // 8 float4-loads per thread per t per chunk
#define NCHUNK (EPQ / CHUNK_E)    // 2 chunks per unit

typedef float vf4 __attribute__((ext_vector_type(4)));

// ---------- helpers ----------

__device__ __forceinline__ void make_k1(float k[KS]) {
    float s = 0.f;
#pragma unroll
    for (int i = 0; i < KS; ++i) {
        float xx = (float)i - 3.0f;
        float t = xx / 1.5f;
        k[i] = expf(-0.5f * t * t);
        s += k[i];
    }
    float inv = 1.0f / s;
#pragma unroll
    for (int i = 0; i < KS; ++i) k[i] *= inv;
}

__device__ __forceinline__ int refl(int z) {
    z = (z < 0) ? -z : z;
    z = (z >= NH) ? (2 * NH - 2 - z) : z;
    return z;
}

__device__ __forceinline__ float rweight(int y, int r, const float k1[KS]) {
    float s = 0.f;
#pragma unroll
    for (int d = 0; d < KS; ++d) {
        int z = y + d - PAD;
        if (refl(z) == r) s += k1[d];
    }
    return s;
}

__device__ __forceinline__ float rwmax(int r, const float k1[KS]) {
    float m = 0.f;
#pragma unroll
    for (int y = 0; y < KS; ++y) m = fmaxf(m, rweight(y, r, k1));
    int lo = max(0, r - PAD), hi = min(NH - 1, r + PAD);
    for (int y = lo; y <= hi; ++y) m = fmaxf(m, rweight(y, r, k1));
#pragma unroll
    for (int y = NH - KS; y < NH; ++y) m = fmaxf(m, rweight(y, r, k1));
    return m;
}

// ---------- kernel 1: chunked LDS-sigmoid argmax ----------
// One block per (bc, quarter): 1024 blocks. Per 8K-element chunk:
//   Phase A: read x chunk once, sigmoid -> LDS (32 KB, 16B-aligned).
//   Phase B: for each t SERIALLY, stream urnd[t] chunk (ONE contiguous
//            DRAM stream per block) against LDS sigmoid, updating the
//            per-t (best,idx) chain held in registers across chunks.
// Each thread reads back only LDS slots it wrote itself; barriers guard
// the chunk overwrite. x and urnd each read exactly once from HBM.

__global__ __launch_bounds__(256, 4) void k_argmax(
        const float* __restrict__ x, const float* __restrict__ urnd,
        float* __restrict__ pmx, int* __restrict__ parg) {
    const int tid = threadIdx.x;
    const int bc = blockIdx.x >> 2;
    const int q = blockIdx.x & (QRT - 1);

    const vf4* x4 = (const vf4*)x + (size_t)bc * (NHW / 4) + q * (EPQ / 4);
    const vf4* u4 = (const vf4*)urnd + (size_t)bc * (NHW / 4) + q * (EPQ / 4);
    const size_t TS = (size_t)NBC * (NHW / 4);   // t-stride in float4 units

    __shared__ __align__(16) float sSig[CHUNK_E];   // 32 KB, 16B-aligned
    vf4* sS4 = (vf4*)sSig;

    float bt[NT];
    int it[NT];
#pragma unroll
    for (int t = 0; t < NT; ++t) { bt[t] = -1.f; it[t] = 0; }

    for (int ch = 0; ch < NCHUNK; ++ch) {
        const int cb4 = ch * CHUNK_V4;           // chunk base in float4 units
        const int cbe = ch * CHUNK_E;            // chunk base in elements

        // ---- phase A: x -> sigmoid -> LDS ----
#pragma unroll 4
        for (int k = 0; k < JITER; ++k) {
            const int v = k * 256 + tid;
            vf4 xx = __builtin_nontemporal_load(x4 + cb4 + v);
            vf4 ss;
            ss[0] = 1.f / (1.f + expf(-xx[0]));
            ss[1] = 1.f / (1.f + expf(-xx[1]));
            ss[2] = 1.f / (1.f + expf(-xx[2]));
            ss[3] = 1.f / (1.f + expf(-xx[3]));
            sS4[v] = ss;
        }
        __syncthreads();

        // ---- phase B: one urnd stream at a time ----
        // t-loop MUST stay fully unrolled: bt[]/it[] need static indexing
        // to live in registers (runtime index -> scratch).
#pragma unroll
        for (int t = 0; t < NT; ++t) {
            const vf4* ut = u4 + (size_t)t * TS + cb4;
#pragma unroll 4
            for (int j = 0; j < JITER; ++j) {
                const int v = j * 256 + tid;
                vf4 uu = __builtin_nontemporal_load(ut + v);
                vf4 ss = sS4[v];
                float p0 = ss[0] * uu[0], p1 = ss[1] * uu[1];
                float p2 = ss[2] * uu[2], p3 = ss[3] * uu[3];
                const int base = cbe + v * 4;
                // strict > keeps first occurrence (ascending scan per thread)
                if (p0 > bt[t]) { bt[t] = p0; it[t] = base; }
                if (p1 > bt[t]) { bt[t] = p1; it[t] = base + 1; }
                if (p2 > bt[t]) { bt[t] = p2; it[t] = base + 2; }
                if (p3 > bt[t]) { bt[t] = p3; it[t] = base + 3; }
            }
        }
        __syncthreads();   // protect sSig before next chunk overwrites
    }

    // wave butterfly reduce per t (tie -> smaller index)
#pragma unroll
    for (int t = 0; t < NT; ++t) {
        float best = bt[t];
        int bidx = it[t];
#pragma unroll
        for (int m = 32; m; m >>= 1) {
            float ov = __shfl_xor(best, m, 64);
            int oi = __shfl_xor(bidx, m, 64);
            if (ov > best || (ov == best && oi < bidx)) { best = ov; bidx = oi; }
        }
        bt[t] = best;
        it[t] = bidx;
    }

    __shared__ float sv[NT][4];
    __shared__ int si[NT][4];
    const int w = tid >> 6;
    if ((tid & 63) == 0) {
#pragma unroll
        for (int t = 0; t < NT; ++t) { sv[t][w] = bt[t]; si[t][w] = it[t]; }
    }
    __syncthreads();
    if (tid < NT) {
        float best = sv[tid][0];
        int bidx = si[tid][0];
#pragma unroll
        for (int ww = 1; ww < 4; ++ww) {
            if (sv[tid][ww] > best || (sv[tid][ww] == best && si[tid][ww] < bidx)) {
                best = sv[tid][ww];
                bidx = si[tid][ww];
            }
        }
        pmx[(tid * NBC + bc) * QRT + q] = best;
        parg[(tid * NBC + bc) * QRT + q] = q * EPQ + bidx;
    }
}

// ---------- kernel 2: fused stats + att write, 1024 blocks ----------

__global__ __launch_bounds__(256, 4) void k_statt(
        const float* __restrict__ pmx, const int* __restrict__ parg,
        float* __restrict__ out_m, float* __restrict__ out_v,
        float* __restrict__ out_vis, float* __restrict__ att) {
    const int tid = threadIdx.x;     // doubles as "bc" for the stats phase
    const int myc = blockIdx.x >> 2; // the plane this block writes
    const int qy = blockIdx.x & 3;   // which 64-row band

    float k1[KS];
    make_k1(k1);

    float ji[NT], jj[NT];
    int visn = 0;
#pragma unroll
    for (int t = 0; t < NT; ++t) {
        int u0 = (t * NBC + tid) * QRT;
        float m = pmx[u0]; int a = parg[u0];
#pragma unroll
        for (int q = 1; q < QRT; ++q) {           // ascending q: ties -> earliest
            float mq = pmx[u0 + q];
            if (mq > m) { m = mq; a = parg[u0 + q]; }
        }
        bool vt = (m >= VIS_TH);
        float ii = (float)(a >> 8) * (1.0f / (float)NH);
        float jv = (float)(a & (NW - 1)) * (1.0f / (float)NW);
        ji[t] = vt ? ii : 0.f;
        jj[t] = vt ? jv : 0.f;
        visn += vt ? 1 : 0;
    }
    float mi = (ji[0] + ji[1] + ji[2] + ji[3] + ji[4]) / 5.0f;
    float mj = (jj[0] + jj[1] + jj[2] + jj[3] + jj[4]) / 5.0f;
    float vi = 0.f, vj = 0.f;
#pragma unroll
    for (int t = 0; t < NT; ++t) {
        float di = ji[t] - mi, dj = jj[t] - mj;
        vi += di * di;
        vj += dj * dj;
    }
    vi /= (float)(NT - 1);
    vj /= (float)(NT - 1);

    bool vis = (visn >= 3);

    if (blockIdx.x == 0) {
        out_m[tid * 2 + 0] = vis ? mi : 0.f;
        out_m[tid * 2 + 1] = vis ? mj : 0.f;
        out_v[tid * 2 + 0] = vis ? vi : 0.f;
        out_v[tid * 2 + 1] = vis ? vj : 0.f;
        out_vis[tid] = vis ? 1.f : 0.f;
    }

    int r = min(max((int)roundf((vis ? mi : 0.f) * (float)NH), 0), NH - 1);
    int c = min(max((int)roundf((vis ? mj : 0.f) * (float)NW), 0), NW - 1);
    float cmax = vis ? (rwmax(r, k1) * rwmax(c, k1)) : 0.f;

    __shared__ int sR[NBC], sC[NBC], sVis[NBC];
    __shared__ float sG[NBC];
    sR[tid] = r; sC[tid] = c; sVis[tid] = vis ? 1 : 0; sG[tid] = cmax;
    __syncthreads();
#pragma unroll
    for (int off = 128; off; off >>= 1) {
        if (tid < off) sG[tid] = fmaxf(sG[tid], sG[tid + off]);
        __syncthreads();
    }
    const float gmax = sG[0];
    const int r_ = sR[myc], c_ = sC[myc], vis_ = sVis[myc];

    // this block's 64-row band: float4 indices qy*4096 + j*256 + tid, j<16
    vf4* out4 = (vf4*)(att + (size_t)myc * NHW) + qy * (NHW / 4 / 4);

    if (!vis_) {          // block-uniform branch (myc same for whole block)
        vf4 z = {0.f, 0.f, 0.f, 0.f};
#pragma unroll
        for (int j = 0; j < 16; ++j)
            __builtin_nontemporal_store(z, out4 + j * 256 + tid);
        return;
    }

    __shared__ float sRW[64];
    if (tid < 64) sRW[tid] = rweight(qy * 64 + tid, r_, k1);
    const int xq = tid & 63;
    const float cw0 = rweight(4 * xq + 0, c_, k1);
    const float cw1 = rweight(4 * xq + 1, c_, k1);
    const float cw2 = rweight(4 * xq + 2, c_, k1);
    const float cw3 = rweight(4 * xq + 3, c_, k1);
    __syncthreads();

    const int w = tid >> 6;
#pragma unroll
    for (int j = 0; j < 16; ++j) {
        float rw = sRW[j * 4 + w];       // wave-uniform broadcast
        vf4 o;
        if (rw == 0.f) {                 // uniform branch: most rows are zero
            o = (vf4){0.f, 0.f, 0.f, 0.f};
        } else {
            float r0 = rw * cw0, r1 = rw * cw1, r2 = rw * cw2, r3 = rw * cw3;
            o[0] = (r0 == 0.f) ? 0.f : (r0 / gmax);
            o[1] = (r1 == 0.f) ? 0.f : (r1 / gmax);
            o[2] = (r2 == 0.f) ? 0.f : (r2 / gmax);
            o[3] = (r3 == 0.f) ? 0.f : (r3 / gmax);
        }
        __builtin_nontemporal_store(o, out4 + j * 256 + tid);
    }
}

// ---------- launcher ----------

extern "C" void kernel_launch(void* const* d_in, const int* in_sizes, int n_in,
                              void* d_out, int out_size, void* d_ws, size_t ws_size,
                              hipStream_t stream) {
    const float* x = (const float*)d_in[0];
    const float* urnd = (const float*)d_in[1];

    float* out = (float*)d_out;
    float* out_att = out;                        // [8,32,256,256]
    float* out_m = out + (size_t)NBC * NHW;      // [8,32,2]
    float* out_v = out_m + NBC * 2;              // [8,32,2]
    float* out_vis = out_v + NBC * 2;            // [8,32]

    char* ws = (char*)d_ws;
    float* pmx = (float*)ws;                ws += NUNITS * sizeof(float);
    int* parg = (int*)ws;

    k_argmax<<<NBC * QRT, 256, 0, stream>>>(x, urnd, pmx, parg);
    k_statt<<<NBC * 4, 256, 0, stream>>>(pmx, parg, out_m, out_v, out_vis, out_att);
}